// Round 1
// baseline (1639.819 us; speedup 1.0000x reference)
//
#include <hip/hip_runtime.h>
#include <hip/hip_bf16.h>
#include <stdint.h>

// ---------------------------------------------------------------------------
// TopKAutoEncoder forward, MI355X.
// acts = (x - pre_bias) @ W_enc + latent_bias   [16384 x 4096], K=4096
// top-64/row (exact selection vs fp64 ref), relu, @ W_dec + pre_bias.
//
// Strategy: fp16 MFMA GEMM for approx acts (error bound E=0.3, 12-sigma),
// exact 64th-value via bitwise binary search, fp64 rescue of the ambiguous
// boundary zone only (~3 candidates/row), bf16 sparse reconstruct with
// XCD-L2-resident W_dec column slabs. acts lives in d_out (overwritten last).
// ---------------------------------------------------------------------------

typedef _Float16 half8 __attribute__((ext_vector_type(8)));
typedef float f32x4 __attribute__((ext_vector_type(4)));
typedef unsigned short ushort8 __attribute__((ext_vector_type(8)));

#define B_ROWS 16384
#define D_DIM  4096
#define TOPK   64
#define EBOUND 0.3f

__device__ __forceinline__ void gload_lds16(const void* g, void* l) {
  __builtin_amdgcn_global_load_lds(
      (const __attribute__((address_space(1))) unsigned int*)g,
      (__attribute__((address_space(3))) unsigned int*)l, 16, 0, 0);
}

__device__ __forceinline__ unsigned f32_sortable(float f) {
  unsigned u = __float_as_uint(f);
  return (u & 0x80000000u) ? ~u : (u | 0x80000000u);
}
__device__ __forceinline__ float sortable_f32(unsigned u) {
  return __uint_as_float((u & 0x80000000u) ? (u & 0x7fffffffu) : ~u);
}
__device__ __forceinline__ unsigned short f2bf(float f) {
  unsigned u = __float_as_uint(f);
  unsigned r = (u + 0x7fffu + ((u >> 16) & 1u)) >> 16;
  return (unsigned short)r;
}

// --------------------------- conversion kernels ----------------------------

__global__ __launch_bounds__(256) void conv_x(
    const float* __restrict__ x, const float* __restrict__ pre_bias,
    _Float16* __restrict__ Xh) {
  size_t g = ((size_t)blockIdx.x * 256 + threadIdx.x) * 8;
  int col = (int)(g & (D_DIM - 1));
  float4 a = *(const float4*)(x + g);
  float4 b = *(const float4*)(x + g + 4);
  float4 p = *(const float4*)(pre_bias + col);
  float4 q = *(const float4*)(pre_bias + col + 4);
  half8 h;
  h[0] = (_Float16)(a.x - p.x); h[1] = (_Float16)(a.y - p.y);
  h[2] = (_Float16)(a.z - p.z); h[3] = (_Float16)(a.w - p.w);
  h[4] = (_Float16)(b.x - q.x); h[5] = (_Float16)(b.y - q.y);
  h[6] = (_Float16)(b.z - q.z); h[7] = (_Float16)(b.w - q.w);
  *(half8*)(Xh + g) = h;
}

// W_enc [K][N] fp32 -> WhT [N][K] fp16  AND WT [N][K] fp32 (for fp64 rescue)
__global__ __launch_bounds__(256) void transp_w(
    const float* __restrict__ W, _Float16* __restrict__ WhT,
    float* __restrict__ WT) {
  __shared__ float tile[64][65];
  int bx = blockIdx.x, by = blockIdx.y;
  int tx = threadIdx.x & 63, ty4 = threadIdx.x >> 6;
  #pragma unroll 4
  for (int i = 0; i < 16; ++i) {
    int r = ty4 * 16 + i;
    tile[r][tx] = W[(size_t)(by * 64 + r) * D_DIM + bx * 64 + tx];
  }
  __syncthreads();
  #pragma unroll 4
  for (int i = 0; i < 16; ++i) {
    int r = ty4 * 16 + i;
    float v = tile[tx][r];
    size_t o = (size_t)(bx * 64 + r) * D_DIM + by * 64 + tx;
    WT[o] = v;
    WhT[o] = (_Float16)v;
  }
}

__global__ __launch_bounds__(256) void conv_wd(
    const float* __restrict__ W, unsigned short* __restrict__ o) {
  size_t g = ((size_t)blockIdx.x * 256 + threadIdx.x) * 8;
  float4 a = *(const float4*)(W + g);
  float4 b = *(const float4*)(W + g + 4);
  ushort8 v;
  v[0] = f2bf(a.x); v[1] = f2bf(a.y); v[2] = f2bf(a.z); v[3] = f2bf(a.w);
  v[4] = f2bf(b.x); v[5] = f2bf(b.y); v[6] = f2bf(b.z); v[7] = f2bf(b.w);
  *(ushort8*)(o + g) = v;
}

// ------------------------------- fp16 GEMM ---------------------------------
// C[M][N] = A[M][K] * Bt[N][K]^T + latent_bias.  128x128 tile, BK=32,
// 4 waves (2x2), 4x4 16x16x32 fragments/wave, global_load_lds width 16.

__global__ __launch_bounds__(256) void gemm_f16(
    const _Float16* __restrict__ A, const _Float16* __restrict__ Bt,
    const float* __restrict__ latent_bias, float* __restrict__ C) {
  __shared__ __align__(16) _Float16 As[128 * 32];
  __shared__ __align__(16) _Float16 Bs[128 * 32];
  const int tid = threadIdx.x;
  const int lane = tid & 63, wave = tid >> 6;
  const int wr = wave >> 1, wc = wave & 1;
  // XCD-aware swizzle (grid=4096, divisible by 8 -> bijective)
  int bid = blockIdx.x;
  int swz = (bid & 7) * (gridDim.x >> 3) + (bid >> 3);
  const int nbn = D_DIM / 128;  // 32
  int bm = swz / nbn, bn = swz % nbn;

  const int r0 = tid >> 2;
  const int kk0 = (tid & 3) << 3;
  const _Float16* Ag0 = A + (size_t)(bm * 128 + r0) * D_DIM + kk0;
  const _Float16* Ag1 = Ag0 + (size_t)64 * D_DIM;
  const _Float16* Bg0 = Bt + (size_t)(bn * 128 + r0) * D_DIM + kk0;
  const _Float16* Bg1 = Bg0 + (size_t)64 * D_DIM;
  _Float16* As0 = &As[wave * 512];          // wave-uniform LDS bases
  _Float16* As1 = &As[2048 + wave * 512];
  _Float16* Bs0 = &Bs[wave * 512];
  _Float16* Bs1 = &Bs[2048 + wave * 512];

  f32x4 acc[4][4];
  #pragma unroll
  for (int i = 0; i < 4; ++i)
    #pragma unroll
    for (int j = 0; j < 4; ++j) acc[i][j] = f32x4{0.f, 0.f, 0.f, 0.f};

  const int fr = lane & 15, fk = (lane >> 4) << 3;
  const int arow0 = (wr * 64 + fr) * 32 + fk;  // + i*16*32
  const int brow0 = (wc * 64 + fr) * 32 + fk;

  for (int kt = 0; kt < D_DIM / 32; ++kt) {
    __syncthreads();
    gload_lds16(Ag0, As0);
    gload_lds16(Ag1, As1);
    gload_lds16(Bg0, Bs0);
    gload_lds16(Bg1, Bs1);
    __syncthreads();
    half8 af[4], bf[4];
    #pragma unroll
    for (int i = 0; i < 4; ++i) {
      af[i] = *(const half8*)&As[arow0 + i * 512];
      bf[i] = *(const half8*)&Bs[brow0 + i * 512];
    }
    #pragma unroll
    for (int i = 0; i < 4; ++i)
      #pragma unroll
      for (int j = 0; j < 4; ++j)
        acc[i][j] = __builtin_amdgcn_mfma_f32_16x16x32_f16(
            af[i], bf[j], acc[i][j], 0, 0, 0);
    Ag0 += 32; Ag1 += 32; Bg0 += 32; Bg1 += 32;
  }
  const int crow = bm * 128 + wr * 64 + ((lane >> 4) << 2);
  const int ccol = bn * 128 + wc * 64 + (lane & 15);
  #pragma unroll
  for (int i = 0; i < 4; ++i)
    #pragma unroll
    for (int j = 0; j < 4; ++j) {
      int col = ccol + j * 16;
      float lb = latent_bias[col];
      #pragma unroll
      for (int r = 0; r < 4; ++r)
        C[(size_t)(crow + i * 16 + r) * D_DIM + col] = acc[i][j][r] + lb;
    }
}

// --------------------------- top-k classify --------------------------------
// Per row: exact 64th-largest approx value T via 32-step bitwise binary
// search on sortable uints in LDS.  certain: a > T+2E; zone: |a-T| <= 2E.
// Deterministic compaction via block prefix scans (no atomics).

__global__ __launch_bounds__(256) void topk_classify(
    const float* __restrict__ acts, float* __restrict__ vals,
    int* __restrict__ idxs, int* __restrict__ ambIdx,
    int* __restrict__ rowMeta) {
  const int row = blockIdx.x;
  const int tid = threadIdx.x;
  const int lane = tid & 63, wave = tid >> 6;
  __shared__ __align__(16) unsigned su[D_DIM];
  __shared__ int sbuf[256];
  const float* arow = acts + (size_t)row * D_DIM;
  #pragma unroll
  for (int i = 0; i < 4; ++i) {
    int d0 = i * 1024 + tid * 4;
    float4 a = *(const float4*)(arow + d0);
    uint4 o;
    o.x = f32_sortable(a.x); o.y = f32_sortable(a.y);
    o.z = f32_sortable(a.z); o.w = f32_sortable(a.w);
    *(uint4*)&su[d0] = o;
  }
  __syncthreads();
  unsigned thr = 0u;
  for (int b = 31; b >= 0; --b) {
    unsigned cand = thr | (1u << b);
    int c = 0;
    #pragma unroll
    for (int i = 0; i < 16; ++i) c += (su[tid + (i << 8)] >= cand) ? 1 : 0;
    #pragma unroll
    for (int off = 32; off; off >>= 1) c += __shfl_down(c, off);
    if (lane == 0) sbuf[wave] = c;
    __syncthreads();
    int tot = sbuf[0] + sbuf[1] + sbuf[2] + sbuf[3];
    if (tot >= TOPK) thr = cand;
    __syncthreads();
  }
  float Tf = sortable_f32(thr);
  unsigned uhi = f32_sortable(Tf + 2.0f * EBOUND);
  unsigned ulo = f32_sortable(Tf - 2.0f * EBOUND);
  int mC = 0, aC = 0;
  #pragma unroll
  for (int i = 0; i < 16; ++i) {
    unsigned u = su[tid + (i << 8)];
    if (u > uhi) ++mC;
    else if (u >= ulo) ++aC;
  }
  // prefix scan for member positions
  sbuf[tid] = mC; __syncthreads();
  for (int off = 1; off < 256; off <<= 1) {
    int v = sbuf[tid];
    int vv = (tid >= off) ? sbuf[tid - off] : 0;
    __syncthreads();
    sbuf[tid] = v + vv;
    __syncthreads();
  }
  int mBase = sbuf[tid] - mC;
  int mTot = sbuf[255];
  __syncthreads();
  sbuf[tid] = aC; __syncthreads();
  for (int off = 1; off < 256; off <<= 1) {
    int v = sbuf[tid];
    int vv = (tid >= off) ? sbuf[tid - off] : 0;
    __syncthreads();
    sbuf[tid] = v + vv;
    __syncthreads();
  }
  int aBase = sbuf[tid] - aC;
  int aTot = sbuf[255];
  int mp = mBase, ap = aBase;
  #pragma unroll
  for (int i = 0; i < 16; ++i) {
    int d = tid + (i << 8);
    unsigned u = su[d];
    if (u > uhi) {
      vals[(size_t)row * TOPK + mp] = fmaxf(sortable_f32(u), 0.0f);
      idxs[(size_t)row * TOPK + mp] = d;
      ++mp;
    } else if (u >= ulo) {
      if (ap < 128) ambIdx[(size_t)row * 128 + ap] = d;
      ++ap;
    }
  }
  if (tid == 0) {
    rowMeta[row * 2 + 0] = mTot;
    rowMeta[row * 2 + 1] = (aTot > 128) ? 128 : aTot;
  }
}

// ------------------------------ fp64 rescue --------------------------------

__global__ __launch_bounds__(256) void rescue(
    const float* __restrict__ x, const float* __restrict__ WT,
    const float* __restrict__ pre_bias, const float* __restrict__ latent_bias,
    const float* __restrict__ acts, const int* __restrict__ ambIdx,
    const int* __restrict__ rowMeta, float* __restrict__ vals,
    int* __restrict__ idxs) {
  const int row = blockIdx.x;
  const int m = rowMeta[row * 2 + 0];
  const int s = rowMeta[row * 2 + 1];
  const int need = TOPK - m;
  const int tid = threadIdx.x;
  if (need <= 0 || s <= 0) return;
  if (s == need) {  // whole zone is in the set; approx values suffice
    if (tid < s) {
      int d = ambIdx[(size_t)row * 128 + tid];
      float v = acts[(size_t)row * D_DIM + d];
      vals[(size_t)row * TOPK + m + tid] = fmaxf(v, 0.0f);
      idxs[(size_t)row * TOPK + m + tid] = d;
    }
    return;
  }
  __shared__ double exv[128];
  const int lane = tid & 63, wave = tid >> 6;
  const float* xr = x + (size_t)row * D_DIM;
  for (int c = wave; c < s; c += 4) {
    int d = ambIdx[(size_t)row * 128 + c];
    const float* wrow = WT + (size_t)d * D_DIM;
    double acc = 0.0;
    #pragma unroll 4
    for (int t = 0; t < 16; ++t) {
      int k0 = t * 256 + lane * 4;
      float4 xv = *(const float4*)(xr + k0);
      float4 pv = *(const float4*)(pre_bias + k0);
      float4 wv = *(const float4*)(wrow + k0);
      acc = fma((double)xv.x - (double)pv.x, (double)wv.x, acc);
      acc = fma((double)xv.y - (double)pv.y, (double)wv.y, acc);
      acc = fma((double)xv.z - (double)pv.z, (double)wv.z, acc);
      acc = fma((double)xv.w - (double)pv.w, (double)wv.w, acc);
    }
    #pragma unroll
    for (int off = 32; off; off >>= 1) acc += __shfl_down(acc, off);
    if (lane == 0) exv[c] = acc + (double)latent_bias[d];
  }
  __syncthreads();
  if (tid == 0) {
    for (int t = 0; t < need; ++t) {
      double best = -1.0e300; int besti = 1 << 30; int bestc = -1;
      for (int c = 0; c < s; ++c) {
        double v = exv[c];
        int d = ambIdx[(size_t)row * 128 + c];
        if (v > best || (v == best && d < besti)) {
          best = v; besti = d; bestc = c;
        }
      }
      vals[(size_t)row * TOPK + m + t] = fmaxf((float)best, 0.0f);
      idxs[(size_t)row * TOPK + m + t] = besti;
      exv[bestc] = -1.0e300;
    }
  }
}

// ----------------------------- reconstruct ---------------------------------
// grid = (B/4) * 8; bid&7 = column slab (512 cols = 4MB bf16 slab of W_dec,
// XCD round-robin keeps each slab L2-resident). 4 rows/block, 1 wave/row.

__global__ __launch_bounds__(256) void reconstruct(
    const unsigned short* __restrict__ Wd, const float* __restrict__ vals,
    const int* __restrict__ idxs, const float* __restrict__ pre_bias,
    float* __restrict__ out) {
  const int bid = blockIdx.x;
  const int cb = bid & 7, rowblk = bid >> 3;
  const int tid = threadIdx.x, lane = tid & 63, wave = tid >> 6;
  const int row = rowblk * 4 + wave;
  const int col0 = cb * 512 + lane * 8;
  __shared__ float sval[256];
  __shared__ int sidx[256];
  sval[tid] = vals[(size_t)(rowblk * 4 + (tid >> 6)) * TOPK + (tid & 63)];
  sidx[tid] = idxs[(size_t)(rowblk * 4 + (tid >> 6)) * TOPK + (tid & 63)];
  __syncthreads();
  float acc[8];
  float4 p0 = *(const float4*)(pre_bias + col0);
  float4 p1 = *(const float4*)(pre_bias + col0 + 4);
  acc[0] = p0.x; acc[1] = p0.y; acc[2] = p0.z; acc[3] = p0.w;
  acc[4] = p1.x; acc[5] = p1.y; acc[6] = p1.z; acc[7] = p1.w;
  #pragma unroll 4
  for (int k = 0; k < TOPK; ++k) {
    float v = sval[wave * 64 + k];
    int d = sidx[wave * 64 + k];
    ushort8 w = *(const ushort8*)(Wd + (size_t)d * D_DIM + col0);
    #pragma unroll
    for (int j = 0; j < 8; ++j)
      acc[j] = fmaf(v, __uint_as_float(((unsigned)w[j]) << 16), acc[j]);
  }
  float4 o0 = {acc[0], acc[1], acc[2], acc[3]};
  float4 o1 = {acc[4], acc[5], acc[6], acc[7]};
  *(float4*)(out + (size_t)row * D_DIM + col0) = o0;
  *(float4*)(out + (size_t)row * D_DIM + col0 + 4) = o1;
}

// ------------------------------- launcher ----------------------------------

extern "C" void kernel_launch(void* const* d_in, const int* in_sizes, int n_in,
                              void* d_out, int out_size, void* d_ws,
                              size_t ws_size, hipStream_t stream) {
  const float* x           = (const float*)d_in[0];
  // d_in[1] = ema_frequency_counter (unused by reference)
  const float* W_enc       = (const float*)d_in[2];
  const float* W_dec       = (const float*)d_in[3];
  const float* pre_bias    = (const float*)d_in[4];
  const float* latent_bias = (const float*)d_in[5];
  float* out = (float*)d_out;  // doubles as acts buffer (same size), then
                               // overwritten by reconstruct.
  char* ws = (char*)d_ws;
  size_t off = 0;
  auto alloc = [&](size_t bytes) {
    size_t o = off;
    off = (off + bytes + 255) & ~(size_t)255;
    return o;
  };
  _Float16* Xh        = (_Float16*)(ws + alloc((size_t)B_ROWS * D_DIM * 2));
  _Float16* WhT       = (_Float16*)(ws + alloc((size_t)D_DIM * D_DIM * 2));
  float* WT           = (float*)(ws + alloc((size_t)D_DIM * D_DIM * 4));
  unsigned short* Wd  = (unsigned short*)(ws + alloc((size_t)D_DIM * D_DIM * 2));
  float* vals         = (float*)(ws + alloc((size_t)B_ROWS * TOPK * 4));
  int* idxs           = (int*)(ws + alloc((size_t)B_ROWS * TOPK * 4));
  int* ambIdx         = (int*)(ws + alloc((size_t)B_ROWS * 128 * 4));
  int* rowMeta        = (int*)(ws + alloc((size_t)B_ROWS * 2 * 4));
  (void)ws_size; (void)in_sizes; (void)n_in; (void)out_size;

  conv_x<<<(B_ROWS * D_DIM / 8) / 256, 256, 0, stream>>>(x, pre_bias, Xh);
  transp_w<<<dim3(D_DIM / 64, D_DIM / 64), 256, 0, stream>>>(W_enc, WhT, WT);
  conv_wd<<<((size_t)D_DIM * D_DIM / 8) / 256, 256, 0, stream>>>(W_dec, Wd);
  gemm_f16<<<(B_ROWS / 128) * (D_DIM / 128), 256, 0, stream>>>(
      Xh, WhT, latent_bias, out);
  topk_classify<<<B_ROWS, 256, 0, stream>>>(out, vals, idxs, ambIdx, rowMeta);
  rescue<<<B_ROWS, 256, 0, stream>>>(x, WT, pre_bias, latent_bias, out,
                                     ambIdx, rowMeta, vals, idxs);
  reconstruct<<<(B_ROWS / 4) * 8, 256, 0, stream>>>(Wd, vals, idxs, pre_bias,
                                                    out);
}

// Round 2
// 1295.226 us; speedup vs baseline: 1.2660x; 1.2660x over previous
//
#include <hip/hip_runtime.h>
#include <hip/hip_bf16.h>
#include <stdint.h>

// ---------------------------------------------------------------------------
// TopKAutoEncoder forward, MI355X.
// acts = (x - pre_bias) @ W_enc + latent_bias   [16384 x 4096]
// top-64/row (exact selection vs ref), relu, @ W_dec + pre_bias.
//
// fp16 MFMA GEMM (256x256 tile, BK=32, 4-deep LDS pipeline, counted vmcnt,
// chunk-XOR LDS swizzle, XCD block swizzle, setprio) -> approx acts (|err|<E).
// Exact-64th-value binary search (register-resident) -> certain / ambiguous.
// fp64 rescue of ambiguous zone. bf16 sparse reconstruct.
// ---------------------------------------------------------------------------

typedef _Float16 half8 __attribute__((ext_vector_type(8)));
typedef float f32x4 __attribute__((ext_vector_type(4)));
typedef unsigned short ushort8 __attribute__((ext_vector_type(8)));

#define B_ROWS 16384
#define D_DIM  4096
#define TOPK   64
#define EBOUND 0.3f
#define NTILES (D_DIM / 32)

__device__ __forceinline__ void gload_lds16(const void* g, void* l) {
  __builtin_amdgcn_global_load_lds(
      (const __attribute__((address_space(1))) unsigned int*)g,
      (__attribute__((address_space(3))) unsigned int*)l, 16, 0, 0);
}

__device__ __forceinline__ unsigned f32_sortable(float f) {
  unsigned u = __float_as_uint(f);
  return (u & 0x80000000u) ? ~u : (u | 0x80000000u);
}
__device__ __forceinline__ float sortable_f32(unsigned u) {
  return __uint_as_float((u & 0x80000000u) ? (u & 0x7fffffffu) : ~u);
}
__device__ __forceinline__ unsigned short f2bf(float f) {
  unsigned u = __float_as_uint(f);
  unsigned r = (u + 0x7fffu + ((u >> 16) & 1u)) >> 16;
  return (unsigned short)r;
}

// --------------------------- conversion kernels ----------------------------

__global__ __launch_bounds__(256) void conv_x(
    const float* __restrict__ x, const float* __restrict__ pre_bias,
    _Float16* __restrict__ Xh) {
  size_t g = ((size_t)blockIdx.x * 256 + threadIdx.x) * 8;
  int col = (int)(g & (D_DIM - 1));
  float4 a = *(const float4*)(x + g);
  float4 b = *(const float4*)(x + g + 4);
  float4 p = *(const float4*)(pre_bias + col);
  float4 q = *(const float4*)(pre_bias + col + 4);
  half8 h;
  h[0] = (_Float16)(a.x - p.x); h[1] = (_Float16)(a.y - p.y);
  h[2] = (_Float16)(a.z - p.z); h[3] = (_Float16)(a.w - p.w);
  h[4] = (_Float16)(b.x - q.x); h[5] = (_Float16)(b.y - q.y);
  h[6] = (_Float16)(b.z - q.z); h[7] = (_Float16)(b.w - q.w);
  *(half8*)(Xh + g) = h;
}

// W_enc [K][N] fp32 -> WhT [N][K] fp16  AND WT [N][K] fp32 (for fp64 rescue)
__global__ __launch_bounds__(256) void transp_w(
    const float* __restrict__ W, _Float16* __restrict__ WhT,
    float* __restrict__ WT) {
  __shared__ float tile[64][65];
  int bx = blockIdx.x, by = blockIdx.y;
  int tx = threadIdx.x & 63, ty4 = threadIdx.x >> 6;
  #pragma unroll 4
  for (int i = 0; i < 16; ++i) {
    int r = ty4 * 16 + i;
    tile[r][tx] = W[(size_t)(by * 64 + r) * D_DIM + bx * 64 + tx];
  }
  __syncthreads();
  #pragma unroll 4
  for (int i = 0; i < 16; ++i) {
    int r = ty4 * 16 + i;
    float v = tile[tx][r];
    size_t o = (size_t)(bx * 64 + r) * D_DIM + by * 64 + tx;
    WT[o] = v;
    WhT[o] = (_Float16)v;
  }
}

__global__ __launch_bounds__(256) void conv_wd(
    const float* __restrict__ W, unsigned short* __restrict__ o) {
  size_t g = ((size_t)blockIdx.x * 256 + threadIdx.x) * 8;
  float4 a = *(const float4*)(W + g);
  float4 b = *(const float4*)(W + g + 4);
  ushort8 v;
  v[0] = f2bf(a.x); v[1] = f2bf(a.y); v[2] = f2bf(a.z); v[3] = f2bf(a.w);
  v[4] = f2bf(b.x); v[5] = f2bf(b.y); v[6] = f2bf(b.z); v[7] = f2bf(b.w);
  *(ushort8*)(o + g) = v;
}

// ------------------------------- fp16 GEMM ---------------------------------
// 256x256 tile, BK=32, 512 threads (8 waves: 2M x 4N), per-wave 128x64 out.
// 4-deep LDS tile pipeline (4 x 32KB = 128KB dynamic LDS): compute tile t
// from buf[t&3] while staging tile t+3 into buf[(t+3)&3] == buf[(t-1)&3]
// (freed at this tile's top barrier). Counted vmcnt(8) per tile, never 0
// until the last tile. Chunk-XOR swizzle i^=(i>>2)&3 applied on BOTH the
// pre-swizzled global source (linear global_load_lds dest) and ds_read addr.

#define TILE_BODY(T, VMSTR)                                                    \
  do {                                                                         \
    asm volatile("s_waitcnt " VMSTR ::: "memory");                             \
    __builtin_amdgcn_s_barrier();                                              \
    asm volatile("" ::: "memory");                                             \
    const int tt3 = (T) + 3;                                                   \
    if (tt3 < NTILES) {                                                        \
      const int bo = (tt3 & 3) * 8192;                                         \
      const int kk = tt3 * 32;                                                 \
      gload_lds16(aSrc0 + kk, AsB + bo + dst0);                                \
      gload_lds16(aSrc1 + kk, AsB + bo + dst1);                                \
    }                                                                          \
    {                                                                          \
      const int ab = ((T) & 3) * 8192;                                         \
      half8 bf[4], af[4];                                                      \
      _Pragma("unroll") for (int nj = 0; nj < 4; ++nj)                         \
          bf[nj] = *(const half8*)(BsB + ab + bBase + nj * 512);               \
      _Pragma("unroll") for (int mi = 0; mi < 4; ++mi)                         \
          af[mi] = *(const half8*)(AsB + ab + aBase + mi * 512);               \
      __builtin_amdgcn_s_setprio(1);                                           \
      _Pragma("unroll") for (int mi = 0; mi < 4; ++mi)                         \
          _Pragma("unroll") for (int nj = 0; nj < 4; ++nj)                     \
          acc[mi][nj] = __builtin_amdgcn_mfma_f32_16x16x32_f16(                \
              af[mi], bf[nj], acc[mi][nj], 0, 0, 0);                           \
      __builtin_amdgcn_s_setprio(0);                                           \
      if (tt3 < NTILES) {                                                      \
        const int bo = (tt3 & 3) * 8192;                                       \
        const int kk = tt3 * 32;                                               \
        gload_lds16(bSrc0 + kk, BsB + bo + dst0);                              \
        gload_lds16(bSrc1 + kk, BsB + bo + dst1);                              \
      }                                                                        \
      _Pragma("unroll") for (int mi = 0; mi < 4; ++mi)                         \
          af[mi] = *(const half8*)(AsB + ab + aBase + (mi + 4) * 512);         \
      __builtin_amdgcn_s_setprio(1);                                           \
      _Pragma("unroll") for (int mi = 0; mi < 4; ++mi)                         \
          _Pragma("unroll") for (int nj = 0; nj < 4; ++nj)                     \
          acc[mi + 4][nj] = __builtin_amdgcn_mfma_f32_16x16x32_f16(            \
              af[mi], bf[nj], acc[mi + 4][nj], 0, 0, 0);                       \
      __builtin_amdgcn_s_setprio(0);                                           \
    }                                                                          \
  } while (0)

__global__ __launch_bounds__(512, 2) void gemm_f16(
    const _Float16* __restrict__ A, const _Float16* __restrict__ Bt,
    const float* __restrict__ latent_bias, float* __restrict__ C) {
  extern __shared__ _Float16 ldsbuf[];
  _Float16* AsB = ldsbuf;            // 4 bufs x 8192 halves (256x32)
  _Float16* BsB = ldsbuf + 4 * 8192;

  const int tid = threadIdx.x;
  const int lane = tid & 63, wave = tid >> 6;
  const int wr = wave >> 2, wc = wave & 3;

  // XCD-aware swizzle; grid = 64*16 = 1024, divisible by 8 -> bijective.
  int bid = blockIdx.x;
  int swz = (bid & 7) * (1024 >> 3) + (bid >> 3);
  const int bmBase = (swz >> 4) * 256;
  const int bnBase = (swz & 15) * 256;

  // staging addresses (chunk i holds logical chunk s = i ^ ((i>>2)&3))
  const int i0 = tid, i1 = 512 + tid;
  const int s0 = i0 ^ ((i0 >> 2) & 3), s1 = i1 ^ ((i1 >> 2) & 3);
  const _Float16* aSrc0 = A + (size_t)(bmBase + (s0 >> 2)) * D_DIM + (s0 & 3) * 8;
  const _Float16* aSrc1 = A + (size_t)(bmBase + (s1 >> 2)) * D_DIM + (s1 & 3) * 8;
  const _Float16* bSrc0 = Bt + (size_t)(bnBase + (s0 >> 2)) * D_DIM + (s0 & 3) * 8;
  const _Float16* bSrc1 = Bt + (size_t)(bnBase + (s1 >> 2)) * D_DIM + (s1 & 3) * 8;
  const int dst0 = i0 * 8, dst1 = i1 * 8;  // halves within buffer

  // fragment read offsets (swizzled): row rr, chunk c4 -> c4 ^ (rr&3)
  const int fr = lane & 15, c4 = lane >> 4;
  const int swzc = (c4 ^ (fr & 3)) * 8;
  const int aBase = (wr * 128 + fr) * 32 + swzc;
  const int bBase = (wc * 64 + fr) * 32 + swzc;

  f32x4 acc[8][4];
  #pragma unroll
  for (int i = 0; i < 8; ++i)
    #pragma unroll
    for (int j = 0; j < 4; ++j) acc[i][j] = f32x4{0.f, 0.f, 0.f, 0.f};

  // prologue: stage tiles 0,1,2 (12 loads)
  #pragma unroll
  for (int tt = 0; tt < 3; ++tt) {
    const int bo = tt * 8192, kk = tt * 32;
    gload_lds16(aSrc0 + kk, AsB + bo + dst0);
    gload_lds16(aSrc1 + kk, AsB + bo + dst1);
    gload_lds16(bSrc0 + kk, BsB + bo + dst0);
    gload_lds16(bSrc1 + kk, BsB + bo + dst1);
  }

  for (int t = 0; t < NTILES - 2; ++t) TILE_BODY(t, "vmcnt(8)");
  TILE_BODY(NTILES - 2, "vmcnt(4)");
  TILE_BODY(NTILES - 1, "vmcnt(0)");

  // epilogue
  const int crow0 = bmBase + wr * 128 + c4 * 4;
  const int ccol0 = bnBase + wc * 64 + fr;
  #pragma unroll
  for (int mi = 0; mi < 8; ++mi)
    #pragma unroll
    for (int nj = 0; nj < 4; ++nj) {
      int col = ccol0 + nj * 16;
      float lb = latent_bias[col];
      #pragma unroll
      for (int r = 0; r < 4; ++r)
        C[(size_t)(crow0 + mi * 16 + r) * D_DIM + col] = acc[mi][nj][r] + lb;
    }
}

// --------------------------- top-k classify --------------------------------
// Register-resident: each thread holds 16 values. 20-step bitwise binary
// search (bits 31..12) for thr <= T64 < thr+2^12; certainty margins widened
// accordingly. Single packed shfl-scan for both compactions.

__global__ __launch_bounds__(256) void topk_classify(
    const float* __restrict__ acts, float* __restrict__ vals,
    int* __restrict__ idxs, int* __restrict__ ambIdx,
    int* __restrict__ rowMeta) {
  const int row = blockIdx.x;
  const int tid = threadIdx.x;
  const int lane = tid & 63, wave = tid >> 6;
  __shared__ int sred[4];
  const float* arow = acts + (size_t)row * D_DIM;
  unsigned su[16];
  #pragma unroll
  for (int i = 0; i < 4; ++i) {
    float4 a = *(const float4*)(arow + i * 1024 + tid * 4);
    su[4 * i + 0] = f32_sortable(a.x);
    su[4 * i + 1] = f32_sortable(a.y);
    su[4 * i + 2] = f32_sortable(a.z);
    su[4 * i + 3] = f32_sortable(a.w);
  }
  unsigned thr = 0u;
  for (int b = 31; b >= 12; --b) {
    unsigned cand = thr | (1u << b);
    int c = 0;
    #pragma unroll
    for (int i = 0; i < 16; ++i) c += (su[i] >= cand) ? 1 : 0;
    #pragma unroll
    for (int off = 32; off; off >>= 1) c += __shfl_down(c, off);
    if (lane == 0) sred[wave] = c;
    __syncthreads();
    int tot = sred[0] + sred[1] + sred[2] + sred[3];
    if (tot >= TOPK) thr = cand;
    __syncthreads();
  }
  // T64 in [sortable(thr), sortable(thr+4096)); widen margins accordingly.
  float Tlo = sortable_f32(thr);
  float Thi = sortable_f32(thr + 4096u);
  unsigned uhi = f32_sortable(Thi + 2.0f * EBOUND);
  unsigned ulo = f32_sortable(Tlo - 2.0f * EBOUND);
  int mC = 0, aC = 0;
  #pragma unroll
  for (int i = 0; i < 16; ++i) {
    unsigned u = su[i];
    if (u > uhi) ++mC;
    else if (u >= ulo) ++aC;
  }
  int xs = mC | (aC << 16);
  #pragma unroll
  for (int off = 1; off < 64; off <<= 1) {
    int y = __shfl_up(xs, off);
    if (lane >= off) xs += y;
  }
  if (lane == 63) sred[wave] = xs;
  __syncthreads();
  int base = 0;
  for (int w = 0; w < 4; ++w)
    if (w < wave) base += sred[w];
  int tot = sred[0] + sred[1] + sred[2] + sred[3];
  int incl = base + xs;
  int mp = (incl & 0xffff) - mC;
  int ap = (incl >> 16) - aC;
  int mTot = tot & 0xffff, aTot = tot >> 16;
  #pragma unroll
  for (int e = 0; e < 16; ++e) {
    unsigned u = su[e];
    int d = (e >> 2) * 1024 + tid * 4 + (e & 3);
    if (u > uhi) {
      vals[(size_t)row * TOPK + mp] = fmaxf(sortable_f32(u), 0.0f);
      idxs[(size_t)row * TOPK + mp] = d;
      ++mp;
    } else if (u >= ulo) {
      if (ap < 128) ambIdx[(size_t)row * 128 + ap] = d;
      ++ap;
    }
  }
  if (tid == 0) {
    rowMeta[row * 2 + 0] = mTot;
    rowMeta[row * 2 + 1] = (aTot > 128) ? 128 : aTot;
  }
}

// ------------------------------ fp64 rescue --------------------------------

__global__ __launch_bounds__(256) void rescue(
    const float* __restrict__ x, const float* __restrict__ WT,
    const float* __restrict__ pre_bias, const float* __restrict__ latent_bias,
    const float* __restrict__ acts, const int* __restrict__ ambIdx,
    const int* __restrict__ rowMeta, float* __restrict__ vals,
    int* __restrict__ idxs) {
  const int row = blockIdx.x;
  const int m = rowMeta[row * 2 + 0];
  const int s = rowMeta[row * 2 + 1];
  const int need = TOPK - m;
  const int tid = threadIdx.x;
  if (need <= 0 || s <= 0) return;
  if (s == need) {  // whole zone is in the set; approx values suffice
    if (tid < s) {
      int d = ambIdx[(size_t)row * 128 + tid];
      float v = acts[(size_t)row * D_DIM + d];
      vals[(size_t)row * TOPK + m + tid] = fmaxf(v, 0.0f);
      idxs[(size_t)row * TOPK + m + tid] = d;
    }
    return;
  }
  __shared__ double exv[128];
  const int lane = tid & 63, wave = tid >> 6;
  const float* xr = x + (size_t)row * D_DIM;
  for (int c = wave; c < s; c += 4) {
    int d = ambIdx[(size_t)row * 128 + c];
    const float* wrow = WT + (size_t)d * D_DIM;
    double acc = 0.0;
    #pragma unroll 4
    for (int t = 0; t < 16; ++t) {
      int k0 = t * 256 + lane * 4;
      float4 xv = *(const float4*)(xr + k0);
      float4 pv = *(const float4*)(pre_bias + k0);
      float4 wv = *(const float4*)(wrow + k0);
      acc = fma((double)xv.x - (double)pv.x, (double)wv.x, acc);
      acc = fma((double)xv.y - (double)pv.y, (double)wv.y, acc);
      acc = fma((double)xv.z - (double)pv.z, (double)wv.z, acc);
      acc = fma((double)xv.w - (double)pv.w, (double)wv.w, acc);
    }
    #pragma unroll
    for (int off = 32; off; off >>= 1) acc += __shfl_down(acc, off);
    if (lane == 0) exv[c] = acc + (double)latent_bias[d];
  }
  __syncthreads();
  if (tid == 0) {
    for (int t = 0; t < need; ++t) {
      double best = -1.0e300; int besti = 1 << 30; int bestc = -1;
      for (int c = 0; c < s; ++c) {
        double v = exv[c];
        int d = ambIdx[(size_t)row * 128 + c];
        if (v > best || (v == best && d < besti)) {
          best = v; besti = d; bestc = c;
        }
      }
      vals[(size_t)row * TOPK + m + t] = fmaxf((float)best, 0.0f);
      idxs[(size_t)row * TOPK + m + t] = besti;
      exv[bestc] = -1.0e300;
    }
  }
}

// ----------------------------- reconstruct ---------------------------------

__global__ __launch_bounds__(256) void reconstruct(
    const unsigned short* __restrict__ Wd, const float* __restrict__ vals,
    const int* __restrict__ idxs, const float* __restrict__ pre_bias,
    float* __restrict__ out) {
  const int bid = blockIdx.x;
  const int cb = bid & 7, rowblk = bid >> 3;
  const int tid = threadIdx.x, lane = tid & 63, wave = tid >> 6;
  const int row = rowblk * 4 + wave;
  const int col0 = cb * 512 + lane * 8;
  __shared__ float sval[256];
  __shared__ int sidx[256];
  sval[tid] = vals[(size_t)(rowblk * 4 + (tid >> 6)) * TOPK + (tid & 63)];
  sidx[tid] = idxs[(size_t)(rowblk * 4 + (tid >> 6)) * TOPK + (tid & 63)];
  __syncthreads();
  float acc[8];
  float4 p0 = *(const float4*)(pre_bias + col0);
  float4 p1 = *(const float4*)(pre_bias + col0 + 4);
  acc[0] = p0.x; acc[1] = p0.y; acc[2] = p0.z; acc[3] = p0.w;
  acc[4] = p1.x; acc[5] = p1.y; acc[6] = p1.z; acc[7] = p1.w;
  #pragma unroll 4
  for (int k = 0; k < TOPK; ++k) {
    float v = sval[wave * 64 + k];
    int d = sidx[wave * 64 + k];
    ushort8 w = *(const ushort8*)(Wd + (size_t)d * D_DIM + col0);
    #pragma unroll
    for (int j = 0; j < 8; ++j)
      acc[j] = fmaf(v, __uint_as_float(((unsigned)w[j]) << 16), acc[j]);
  }
  float4 o0 = {acc[0], acc[1], acc[2], acc[3]};
  float4 o1 = {acc[4], acc[5], acc[6], acc[7]};
  *(float4*)(out + (size_t)row * D_DIM + col0) = o0;
  *(float4*)(out + (size_t)row * D_DIM + col0 + 4) = o1;
}

// ------------------------------- launcher ----------------------------------

extern "C" void kernel_launch(void* const* d_in, const int* in_sizes, int n_in,
                              void* d_out, int out_size, void* d_ws,
                              size_t ws_size, hipStream_t stream) {
  const float* x           = (const float*)d_in[0];
  // d_in[1] = ema_frequency_counter (unused by reference)
  const float* W_enc       = (const float*)d_in[2];
  const float* W_dec       = (const float*)d_in[3];
  const float* pre_bias    = (const float*)d_in[4];
  const float* latent_bias = (const float*)d_in[5];
  float* out = (float*)d_out;  // doubles as acts buffer, overwritten last
  char* ws = (char*)d_ws;
  size_t off = 0;
  auto alloc = [&](size_t bytes) {
    size_t o = off;
    off = (off + bytes + 255) & ~(size_t)255;
    return o;
  };
  _Float16* Xh        = (_Float16*)(ws + alloc((size_t)B_ROWS * D_DIM * 2));
  _Float16* WhT       = (_Float16*)(ws + alloc((size_t)D_DIM * D_DIM * 2));
  float* WT           = (float*)(ws + alloc((size_t)D_DIM * D_DIM * 4));
  unsigned short* Wd  = (unsigned short*)(ws + alloc((size_t)D_DIM * D_DIM * 2));
  float* vals         = (float*)(ws + alloc((size_t)B_ROWS * TOPK * 4));
  int* idxs           = (int*)(ws + alloc((size_t)B_ROWS * TOPK * 4));
  int* ambIdx         = (int*)(ws + alloc((size_t)B_ROWS * 128 * 4));
  int* rowMeta        = (int*)(ws + alloc((size_t)B_ROWS * 2 * 4));
  (void)ws_size; (void)in_sizes; (void)n_in; (void)out_size;

  // allow 128KB dynamic LDS for the GEMM (cheap, deterministic, idempotent)
  (void)hipFuncSetAttribute((const void*)gemm_f16,
                            hipFuncAttributeMaxDynamicSharedMemorySize,
                            131072);

  conv_x<<<(B_ROWS * D_DIM / 8) / 256, 256, 0, stream>>>(x, pre_bias, Xh);
  transp_w<<<dim3(D_DIM / 64, D_DIM / 64), 256, 0, stream>>>(W_enc, WhT, WT);
  conv_wd<<<((size_t)D_DIM * D_DIM / 8) / 256, 256, 0, stream>>>(W_dec, Wd);
  gemm_f16<<<(B_ROWS / 256) * (D_DIM / 256), 512, 131072, stream>>>(
      Xh, WhT, latent_bias, out);
  topk_classify<<<B_ROWS, 256, 0, stream>>>(out, vals, idxs, ambIdx, rowMeta);
  rescue<<<B_ROWS, 256, 0, stream>>>(x, WT, pre_bias, latent_bias, out,
                                     ambIdx, rowMeta, vals, idxs);
  reconstruct<<<(B_ROWS / 4) * 8, 256, 0, stream>>>(Wd, vals, idxs, pre_bias,
                                                    out);
}

// Round 3
// 1284.614 us; speedup vs baseline: 1.2765x; 1.0083x over previous
//
#include <hip/hip_runtime.h>
#include <hip/hip_bf16.h>
#include <stdint.h>

// ---------------------------------------------------------------------------
// TopKAutoEncoder forward, MI355X.
// acts = (x - pre_bias) @ W_enc + latent_bias   [16384 x 4096]
// top-64/row (exact selection vs ref), relu, @ W_dec + pre_bias.
//
// fp16 MFMA GEMM (256x256 tile, BK=32, 4-deep LDS pipeline, counted vmcnt,
// chunk-XOR LDS swizzle f(r)=(r>>1)&3 [2-way/free], XCD block swizzle,
// setprio) -> approx acts (|err|<E).  Exact-64th-value binary search
// (register-resident) -> certain / ambiguous.  fp64 rescue of ambiguous
// zone.  bf16 sparse reconstruct with XCD-L2-resident W_dec slabs.
// ---------------------------------------------------------------------------

typedef _Float16 half8 __attribute__((ext_vector_type(8)));
typedef float f32x4 __attribute__((ext_vector_type(4)));
typedef unsigned short ushort8 __attribute__((ext_vector_type(8)));

#define B_ROWS 16384
#define D_DIM  4096
#define TOPK   64
#define EBOUND 0.3f
#define NTILES (D_DIM / 32)

__device__ __forceinline__ void gload_lds16(const void* g, void* l) {
  __builtin_amdgcn_global_load_lds(
      (const __attribute__((address_space(1))) unsigned int*)g,
      (__attribute__((address_space(3))) unsigned int*)l, 16, 0, 0);
}

__device__ __forceinline__ unsigned f32_sortable(float f) {
  unsigned u = __float_as_uint(f);
  return (u & 0x80000000u) ? ~u : (u | 0x80000000u);
}
__device__ __forceinline__ float sortable_f32(unsigned u) {
  return __uint_as_float((u & 0x80000000u) ? (u & 0x7fffffffu) : ~u);
}
__device__ __forceinline__ unsigned short f2bf(float f) {
  unsigned u = __float_as_uint(f);
  unsigned r = (u + 0x7fffu + ((u >> 16) & 1u)) >> 16;
  return (unsigned short)r;
}

// --------------------------- conversion kernels ----------------------------

__global__ __launch_bounds__(256) void conv_x(
    const float* __restrict__ x, const float* __restrict__ pre_bias,
    _Float16* __restrict__ Xh) {
  size_t g = ((size_t)blockIdx.x * 256 + threadIdx.x) * 8;
  int col = (int)(g & (D_DIM - 1));
  float4 a = *(const float4*)(x + g);
  float4 b = *(const float4*)(x + g + 4);
  float4 p = *(const float4*)(pre_bias + col);
  float4 q = *(const float4*)(pre_bias + col + 4);
  half8 h;
  h[0] = (_Float16)(a.x - p.x); h[1] = (_Float16)(a.y - p.y);
  h[2] = (_Float16)(a.z - p.z); h[3] = (_Float16)(a.w - p.w);
  h[4] = (_Float16)(b.x - q.x); h[5] = (_Float16)(b.y - q.y);
  h[6] = (_Float16)(b.z - q.z); h[7] = (_Float16)(b.w - q.w);
  *(half8*)(Xh + g) = h;
}

// W_enc [K][N] fp32 -> WhT [N][K] fp16  AND WT [N][K] fp32 (for fp64 rescue)
__global__ __launch_bounds__(256) void transp_w(
    const float* __restrict__ W, _Float16* __restrict__ WhT,
    float* __restrict__ WT) {
  __shared__ float tile[64][65];
  int bx = blockIdx.x, by = blockIdx.y;
  int tx = threadIdx.x & 63, ty4 = threadIdx.x >> 6;
  #pragma unroll 4
  for (int i = 0; i < 16; ++i) {
    int r = ty4 * 16 + i;
    tile[r][tx] = W[(size_t)(by * 64 + r) * D_DIM + bx * 64 + tx];
  }
  __syncthreads();
  #pragma unroll 4
  for (int i = 0; i < 16; ++i) {
    int r = ty4 * 16 + i;
    float v = tile[tx][r];
    size_t o = (size_t)(bx * 64 + r) * D_DIM + by * 64 + tx;
    WT[o] = v;
    WhT[o] = (_Float16)v;
  }
}

__global__ __launch_bounds__(256) void conv_wd(
    const float* __restrict__ W, unsigned short* __restrict__ o) {
  size_t g = ((size_t)blockIdx.x * 256 + threadIdx.x) * 8;
  float4 a = *(const float4*)(W + g);
  float4 b = *(const float4*)(W + g + 4);
  ushort8 v;
  v[0] = f2bf(a.x); v[1] = f2bf(a.y); v[2] = f2bf(a.z); v[3] = f2bf(a.w);
  v[4] = f2bf(b.x); v[5] = f2bf(b.y); v[6] = f2bf(b.z); v[7] = f2bf(b.w);
  *(ushort8*)(o + g) = v;
}

// ------------------------------- fp16 GEMM ---------------------------------
// 256x256 tile, BK=32, 512 threads (8 waves: 2M x 4N), per-wave 128x64 out.
// 4-deep LDS tile pipeline (4 x 32KB = 128KB dynamic LDS): compute tile t
// from buf[t&3] while staging tile t+3 into buf[(t+3)&3] == buf[(t-1)&3]
// (freed at this tile's top barrier). Counted vmcnt(8) per tile, never 0
// until the last tile. Chunk-XOR swizzle: physical chunk i holds logical
// chunk i ^ ((i>>3)&3)  [f(row)=(row>>1)&3] -> bank group (row&1)*4 +
// (c4 ^ f(row)) covers all 8 groups exactly 2x per quarter-wave (free).

#define TILE_BODY(T, VMSTR)                                                    \
  do {                                                                         \
    asm volatile("s_waitcnt " VMSTR ::: "memory");                             \
    __builtin_amdgcn_s_barrier();                                              \
    asm volatile("" ::: "memory");                                             \
    const int tt3 = (T) + 3;                                                   \
    if (tt3 < NTILES) {                                                        \
      const int bo = (tt3 & 3) * 8192;                                         \
      const int kk = tt3 * 32;                                                 \
      gload_lds16(aSrc0 + kk, AsB + bo + dst0);                                \
      gload_lds16(aSrc1 + kk, AsB + bo + dst1);                                \
    }                                                                          \
    {                                                                          \
      const int ab = ((T) & 3) * 8192;                                         \
      half8 bf[4], af[4];                                                      \
      _Pragma("unroll") for (int nj = 0; nj < 4; ++nj)                         \
          bf[nj] = *(const half8*)(BsB + ab + bBase + nj * 512);               \
      _Pragma("unroll") for (int mi = 0; mi < 4; ++mi)                         \
          af[mi] = *(const half8*)(AsB + ab + aBase + mi * 512);               \
      __builtin_amdgcn_s_setprio(1);                                           \
      _Pragma("unroll") for (int mi = 0; mi < 4; ++mi)                         \
          _Pragma("unroll") for (int nj = 0; nj < 4; ++nj)                     \
          acc[mi][nj] = __builtin_amdgcn_mfma_f32_16x16x32_f16(                \
              af[mi], bf[nj], acc[mi][nj], 0, 0, 0);                           \
      __builtin_amdgcn_s_setprio(0);                                           \
      if (tt3 < NTILES) {                                                      \
        const int bo = (tt3 & 3) * 8192;                                       \
        const int kk = tt3 * 32;                                               \
        gload_lds16(bSrc0 + kk, BsB + bo + dst0);                              \
        gload_lds16(bSrc1 + kk, BsB + bo + dst1);                              \
      }                                                                        \
      _Pragma("unroll") for (int mi = 0; mi < 4; ++mi)                         \
          af[mi] = *(const half8*)(AsB + ab + aBase + (mi + 4) * 512);         \
      __builtin_amdgcn_s_setprio(1);                                           \
      _Pragma("unroll") for (int mi = 0; mi < 4; ++mi)                         \
          _Pragma("unroll") for (int nj = 0; nj < 4; ++nj)                     \
          acc[mi + 4][nj] = __builtin_amdgcn_mfma_f32_16x16x32_f16(            \
              af[mi], bf[nj], acc[mi + 4][nj], 0, 0, 0);                       \
      __builtin_amdgcn_s_setprio(0);                                           \
    }                                                                          \
  } while (0)

__global__ __launch_bounds__(512, 2) void gemm_f16(
    const _Float16* __restrict__ A, const _Float16* __restrict__ Bt,
    const float* __restrict__ latent_bias, float* __restrict__ C) {
  extern __shared__ _Float16 ldsbuf[];
  _Float16* AsB = ldsbuf;            // 4 bufs x 8192 halves (256x32)
  _Float16* BsB = ldsbuf + 4 * 8192;

  const int tid = threadIdx.x;
  const int lane = tid & 63, wave = tid >> 6;
  const int wr = wave >> 2, wc = wave & 3;

  // XCD-aware swizzle; grid = 64*16 = 1024, divisible by 8 -> bijective.
  int bid = blockIdx.x;
  int swz = (bid & 7) * (1024 >> 3) + (bid >> 3);
  const int bmBase = (swz >> 4) * 256;
  const int bnBase = (swz & 15) * 256;

  // staging: physical chunk i holds logical chunk s = i ^ ((i>>3)&3)
  const int i0 = tid, i1 = 512 + tid;
  const int s0 = i0 ^ ((i0 >> 3) & 3), s1 = i1 ^ ((i1 >> 3) & 3);
  const _Float16* aSrc0 = A + (size_t)(bmBase + (s0 >> 2)) * D_DIM + (s0 & 3) * 8;
  const _Float16* aSrc1 = A + (size_t)(bmBase + (s1 >> 2)) * D_DIM + (s1 & 3) * 8;
  const _Float16* bSrc0 = Bt + (size_t)(bnBase + (s0 >> 2)) * D_DIM + (s0 & 3) * 8;
  const _Float16* bSrc1 = Bt + (size_t)(bnBase + (s1 >> 2)) * D_DIM + (s1 & 3) * 8;
  const int dst0 = i0 * 8, dst1 = i1 * 8;  // halves within buffer (linear)

  // fragment reads: logical chunk c4 of row fr sits at physical chunk
  // c4 ^ ((fr>>1)&3)  (full-row bits 1-2 == fr bits 1-2: offsets are x16)
  const int fr = lane & 15, c4 = lane >> 4;
  const int swzc = (c4 ^ ((fr >> 1) & 3)) * 8;
  const int aBase = (wr * 128 + fr) * 32 + swzc;
  const int bBase = (wc * 64 + fr) * 32 + swzc;

  f32x4 acc[8][4];
  #pragma unroll
  for (int i = 0; i < 8; ++i)
    #pragma unroll
    for (int j = 0; j < 4; ++j) acc[i][j] = f32x4{0.f, 0.f, 0.f, 0.f};

  // prologue: stage tiles 0,1,2 (12 loads)
  #pragma unroll
  for (int tt = 0; tt < 3; ++tt) {
    const int bo = tt * 8192, kk = tt * 32;
    gload_lds16(aSrc0 + kk, AsB + bo + dst0);
    gload_lds16(aSrc1 + kk, AsB + bo + dst1);
    gload_lds16(bSrc0 + kk, BsB + bo + dst0);
    gload_lds16(bSrc1 + kk, BsB + bo + dst1);
  }

  for (int t = 0; t < NTILES - 2; ++t) TILE_BODY(t, "vmcnt(8)");
  TILE_BODY(NTILES - 2, "vmcnt(4)");
  TILE_BODY(NTILES - 1, "vmcnt(0)");

  // epilogue
  const int crow0 = bmBase + wr * 128 + c4 * 4;
  const int ccol0 = bnBase + wc * 64 + fr;
  #pragma unroll
  for (int mi = 0; mi < 8; ++mi)
    #pragma unroll
    for (int nj = 0; nj < 4; ++nj) {
      int col = ccol0 + nj * 16;
      float lb = latent_bias[col];
      #pragma unroll
      for (int r = 0; r < 4; ++r)
        C[(size_t)(crow0 + mi * 16 + r) * D_DIM + col] = acc[mi][nj][r] + lb;
    }
}

// --------------------------- top-k classify --------------------------------
// Register-resident: each thread holds 16 values. 20-step bitwise binary
// search (bits 31..12) for thr <= T64 < thr+2^12; certainty margins widened
// accordingly. Single packed shfl-scan for both compactions.

__global__ __launch_bounds__(256) void topk_classify(
    const float* __restrict__ acts, float* __restrict__ vals,
    int* __restrict__ idxs, int* __restrict__ ambIdx,
    int* __restrict__ rowMeta) {
  const int row = blockIdx.x;
  const int tid = threadIdx.x;
  const int lane = tid & 63, wave = tid >> 6;
  __shared__ int sred[4];
  const float* arow = acts + (size_t)row * D_DIM;
  unsigned su[16];
  #pragma unroll
  for (int i = 0; i < 4; ++i) {
    float4 a = *(const float4*)(arow + i * 1024 + tid * 4);
    su[4 * i + 0] = f32_sortable(a.x);
    su[4 * i + 1] = f32_sortable(a.y);
    su[4 * i + 2] = f32_sortable(a.z);
    su[4 * i + 3] = f32_sortable(a.w);
  }
  unsigned thr = 0u;
  for (int b = 31; b >= 12; --b) {
    unsigned cand = thr | (1u << b);
    int c = 0;
    #pragma unroll
    for (int i = 0; i < 16; ++i) c += (su[i] >= cand) ? 1 : 0;
    #pragma unroll
    for (int off = 32; off; off >>= 1) c += __shfl_down(c, off);
    if (lane == 0) sred[wave] = c;
    __syncthreads();
    int tot = sred[0] + sred[1] + sred[2] + sred[3];
    if (tot >= TOPK) thr = cand;
    __syncthreads();
  }
  // T64 in [sortable(thr), sortable(thr+4096)); widen margins accordingly.
  float Tlo = sortable_f32(thr);
  float Thi = sortable_f32(thr + 4096u);
  unsigned uhi = f32_sortable(Thi + 2.0f * EBOUND);
  unsigned ulo = f32_sortable(Tlo - 2.0f * EBOUND);
  int mC = 0, aC = 0;
  #pragma unroll
  for (int i = 0; i < 16; ++i) {
    unsigned u = su[i];
    if (u > uhi) ++mC;
    else if (u >= ulo) ++aC;
  }
  int xs = mC | (aC << 16);
  #pragma unroll
  for (int off = 1; off < 64; off <<= 1) {
    int y = __shfl_up(xs, off);
    if (lane >= off) xs += y;
  }
  if (lane == 63) sred[wave] = xs;
  __syncthreads();
  int base = 0;
  for (int w = 0; w < 4; ++w)
    if (w < wave) base += sred[w];
  int tot = sred[0] + sred[1] + sred[2] + sred[3];
  int incl = base + xs;
  int mp = (incl & 0xffff) - mC;
  int ap = (incl >> 16) - aC;
  int mTot = tot & 0xffff, aTot = tot >> 16;
  #pragma unroll
  for (int e = 0; e < 16; ++e) {
    unsigned u = su[e];
    int d = (e >> 2) * 1024 + tid * 4 + (e & 3);
    if (u > uhi) {
      vals[(size_t)row * TOPK + mp] = fmaxf(sortable_f32(u), 0.0f);
      idxs[(size_t)row * TOPK + mp] = d;
      ++mp;
    } else if (u >= ulo) {
      if (ap < 128) ambIdx[(size_t)row * 128 + ap] = d;
      ++ap;
    }
  }
  if (tid == 0) {
    rowMeta[row * 2 + 0] = mTot;
    rowMeta[row * 2 + 1] = (aTot > 128) ? 128 : aTot;
  }
}

// ------------------------------ fp64 rescue --------------------------------

__global__ __launch_bounds__(256) void rescue(
    const float* __restrict__ x, const float* __restrict__ WT,
    const float* __restrict__ pre_bias, const float* __restrict__ latent_bias,
    const float* __restrict__ acts, const int* __restrict__ ambIdx,
    const int* __restrict__ rowMeta, float* __restrict__ vals,
    int* __restrict__ idxs) {
  const int row = blockIdx.x;
  const int m = rowMeta[row * 2 + 0];
  const int s = rowMeta[row * 2 + 1];
  const int need = TOPK - m;
  const int tid = threadIdx.x;
  if (need <= 0 || s <= 0) return;
  if (s == need) {  // whole zone is in the set; approx values suffice
    if (tid < s) {
      int d = ambIdx[(size_t)row * 128 + tid];
      float v = acts[(size_t)row * D_DIM + d];
      vals[(size_t)row * TOPK + m + tid] = fmaxf(v, 0.0f);
      idxs[(size_t)row * TOPK + m + tid] = d;
    }
    return;
  }
  __shared__ double exv[128];
  const int lane = tid & 63, wave = tid >> 6;
  const float* xr = x + (size_t)row * D_DIM;
  for (int c = wave; c < s; c += 4) {
    int d = ambIdx[(size_t)row * 128 + c];
    const float* wrow = WT + (size_t)d * D_DIM;
    double acc = 0.0;
    #pragma unroll 4
    for (int t = 0; t < 16; ++t) {
      int k0 = t * 256 + lane * 4;
      float4 xv = *(const float4*)(xr + k0);
      float4 pv = *(const float4*)(pre_bias + k0);
      float4 wv = *(const float4*)(wrow + k0);
      acc = fma((double)xv.x - (double)pv.x, (double)wv.x, acc);
      acc = fma((double)xv.y - (double)pv.y, (double)wv.y, acc);
      acc = fma((double)xv.z - (double)pv.z, (double)wv.z, acc);
      acc = fma((double)xv.w - (double)pv.w, (double)wv.w, acc);
    }
    #pragma unroll
    for (int off = 32; off; off >>= 1) acc += __shfl_down(acc, off);
    if (lane == 0) exv[c] = acc + (double)latent_bias[d];
  }
  __syncthreads();
  if (tid == 0) {
    for (int t = 0; t < need; ++t) {
      double best = -1.0e300; int besti = 1 << 30; int bestc = -1;
      for (int c = 0; c < s; ++c) {
        double v = exv[c];
        int d = ambIdx[(size_t)row * 128 + c];
        if (v > best || (v == best && d < besti)) {
          best = v; besti = d; bestc = c;
        }
      }
      vals[(size_t)row * TOPK + m + t] = fmaxf((float)best, 0.0f);
      idxs[(size_t)row * TOPK + m + t] = besti;
      exv[bestc] = -1.0e300;
    }
  }
}

// ----------------------------- reconstruct ---------------------------------

__global__ __launch_bounds__(256) void reconstruct(
    const unsigned short* __restrict__ Wd, const float* __restrict__ vals,
    const int* __restrict__ idxs, const float* __restrict__ pre_bias,
    float* __restrict__ out) {
  const int bid = blockIdx.x;
  const int cb = bid & 7, rowblk = bid >> 3;
  const int tid = threadIdx.x, lane = tid & 63, wave = tid >> 6;
  const int row = rowblk * 4 + wave;
  const int col0 = cb * 512 + lane * 8;
  __shared__ float sval[256];
  __shared__ int sidx[256];
  sval[tid] = vals[(size_t)(rowblk * 4 + (tid >> 6)) * TOPK + (tid & 63)];
  sidx[tid] = idxs[(size_t)(rowblk * 4 + (tid >> 6)) * TOPK + (tid & 63)];
  __syncthreads();
  float acc[8];
  float4 p0 = *(const float4*)(pre_bias + col0);
  float4 p1 = *(const float4*)(pre_bias + col0 + 4);
  acc[0] = p0.x; acc[1] = p0.y; acc[2] = p0.z; acc[3] = p0.w;
  acc[4] = p1.x; acc[5] = p1.y; acc[6] = p1.z; acc[7] = p1.w;
  #pragma unroll 4
  for (int k = 0; k < TOPK; ++k) {
    float v = sval[wave * 64 + k];
    int d = sidx[wave * 64 + k];
    ushort8 w = *(const ushort8*)(Wd + (size_t)d * D_DIM + col0);
    #pragma unroll
    for (int j = 0; j < 8; ++j)
      acc[j] = fmaf(v, __uint_as_float(((unsigned)w[j]) << 16), acc[j]);
  }
  float4 o0 = {acc[0], acc[1], acc[2], acc[3]};
  float4 o1 = {acc[4], acc[5], acc[6], acc[7]};
  *(float4*)(out + (size_t)row * D_DIM + col0) = o0;
  *(float4*)(out + (size_t)row * D_DIM + col0 + 4) = o1;
}

// ------------------------------- launcher ----------------------------------

extern "C" void kernel_launch(void* const* d_in, const int* in_sizes, int n_in,
                              void* d_out, int out_size, void* d_ws,
                              size_t ws_size, hipStream_t stream) {
  const float* x           = (const float*)d_in[0];
  // d_in[1] = ema_frequency_counter (unused by reference)
  const float* W_enc       = (const float*)d_in[2];
  const float* W_dec       = (const float*)d_in[3];
  const float* pre_bias    = (const float*)d_in[4];
  const float* latent_bias = (const float*)d_in[5];
  float* out = (float*)d_out;  // doubles as acts buffer, overwritten last
  char* ws = (char*)d_ws;
  size_t off = 0;
  auto alloc = [&](size_t bytes) {
    size_t o = off;
    off = (off + bytes + 255) & ~(size_t)255;
    return o;
  };
  _Float16* Xh        = (_Float16*)(ws + alloc((size_t)B_ROWS * D_DIM * 2));
  _Float16* WhT       = (_Float16*)(ws + alloc((size_t)D_DIM * D_DIM * 2));
  float* WT           = (float*)(ws + alloc((size_t)D_DIM * D_DIM * 4));
  unsigned short* Wd  = (unsigned short*)(ws + alloc((size_t)D_DIM * D_DIM * 2));
  float* vals         = (float*)(ws + alloc((size_t)B_ROWS * TOPK * 4));
  int* idxs           = (int*)(ws + alloc((size_t)B_ROWS * TOPK * 4));
  int* ambIdx         = (int*)(ws + alloc((size_t)B_ROWS * 128 * 4));
  int* rowMeta        = (int*)(ws + alloc((size_t)B_ROWS * 2 * 4));
  (void)ws_size; (void)in_sizes; (void)n_in; (void)out_size;

  // allow 128KB dynamic LDS for the GEMM (cheap, deterministic, idempotent)
  (void)hipFuncSetAttribute((const void*)gemm_f16,
                            hipFuncAttributeMaxDynamicSharedMemorySize,
                            131072);

  conv_x<<<(B_ROWS * D_DIM / 8) / 256, 256, 0, stream>>>(x, pre_bias, Xh);
  transp_w<<<dim3(D_DIM / 64, D_DIM / 64), 256, 0, stream>>>(W_enc, WhT, WT);
  conv_wd<<<((size_t)D_DIM * D_DIM / 8) / 256, 256, 0, stream>>>(W_dec, Wd);
  gemm_f16<<<(B_ROWS / 256) * (D_DIM / 256), 512, 131072, stream>>>(
      Xh, WhT, latent_bias, out);
  topk_classify<<<B_ROWS, 256, 0, stream>>>(out, vals, idxs, ambIdx, rowMeta);
  rescue<<<B_ROWS, 256, 0, stream>>>(x, WT, pre_bias, latent_bias, out,
                                     ambIdx, rowMeta, vals, idxs);
  reconstruct<<<(B_ROWS / 4) * 8, 256, 0, stream>>>(Wd, vals, idxs, pre_bias,
                                                    out);
}

// Round 5
// 1208.528 us; speedup vs baseline: 1.3569x; 1.0630x over previous
//
#include <hip/hip_runtime.h>
#include <hip/hip_bf16.h>
#include <stdint.h>

// ---------------------------------------------------------------------------
// TopKAutoEncoder forward, MI355X.
// acts = (x - pre_bias) @ W_enc + latent_bias   [16384 x 4096]
// top-64/row (exact selection vs ref), relu, @ W_dec + pre_bias.
//
// fp16 MFMA GEMM: 256x256 tile, BK=32, 4-deep LDS pipeline, counted vmcnt,
// chunk-XOR LDS swizzle (bank-conflict-free), XCD block swizzle, setprio,
// + REGISTER double-buffered fragments (prefetch tile t+1's LDS->reg reads
// during tile t's MFMAs). R5 fix: barrier between prologue vmcnt(8) and
// PREFETCH(0) -- vmcnt only orders a wave's OWN loads; fragment reads span
// data staged by other waves.
// Exact-64th-value binary search -> certain / ambiguous (margin 0.25).
// fp64 rescue of ambiguous zone (fast-path resolved in classify).
// bf16 sparse reconstruct with XCD-L2-resident W_dec slabs.
// ---------------------------------------------------------------------------

typedef _Float16 half8 __attribute__((ext_vector_type(8)));
typedef float f32x4 __attribute__((ext_vector_type(4)));
typedef unsigned short ushort8 __attribute__((ext_vector_type(8)));

#define B_ROWS 16384
#define D_DIM  4096
#define TOPK   64
#define MARGIN 0.25f
#define NTILES (D_DIM / 32)

__device__ __forceinline__ void gload_lds16(const void* g, void* l) {
  __builtin_amdgcn_global_load_lds(
      (const __attribute__((address_space(1))) unsigned int*)g,
      (__attribute__((address_space(3))) unsigned int*)l, 16, 0, 0);
}

__device__ __forceinline__ unsigned f32_sortable(float f) {
  unsigned u = __float_as_uint(f);
  return (u & 0x80000000u) ? ~u : (u | 0x80000000u);
}
__device__ __forceinline__ float sortable_f32(unsigned u) {
  return __uint_as_float((u & 0x80000000u) ? (u & 0x7fffffffu) : ~u);
}
__device__ __forceinline__ unsigned short f2bf(float f) {
  unsigned u = __float_as_uint(f);
  unsigned r = (u + 0x7fffu + ((u >> 16) & 1u)) >> 16;
  return (unsigned short)r;
}

// --------------------------- conversion kernels ----------------------------

__global__ __launch_bounds__(256) void conv_x(
    const float* __restrict__ x, const float* __restrict__ pre_bias,
    _Float16* __restrict__ Xh) {
  size_t g = ((size_t)blockIdx.x * 256 + threadIdx.x) * 8;
  int col = (int)(g & (D_DIM - 1));
  float4 a = *(const float4*)(x + g);
  float4 b = *(const float4*)(x + g + 4);
  float4 p = *(const float4*)(pre_bias + col);
  float4 q = *(const float4*)(pre_bias + col + 4);
  half8 h;
  h[0] = (_Float16)(a.x - p.x); h[1] = (_Float16)(a.y - p.y);
  h[2] = (_Float16)(a.z - p.z); h[3] = (_Float16)(a.w - p.w);
  h[4] = (_Float16)(b.x - q.x); h[5] = (_Float16)(b.y - q.y);
  h[6] = (_Float16)(b.z - q.z); h[7] = (_Float16)(b.w - q.w);
  *(half8*)(Xh + g) = h;
}

// W_enc [K][N] fp32 -> WhT [N][K] fp16  AND WT [N][K] fp32 (for fp64 rescue)
__global__ __launch_bounds__(256) void transp_w(
    const float* __restrict__ W, _Float16* __restrict__ WhT,
    float* __restrict__ WT) {
  __shared__ float tile[64][65];
  int bx = blockIdx.x, by = blockIdx.y;
  int tx = threadIdx.x & 63, ty4 = threadIdx.x >> 6;
  #pragma unroll 4
  for (int i = 0; i < 16; ++i) {
    int r = ty4 * 16 + i;
    tile[r][tx] = W[(size_t)(by * 64 + r) * D_DIM + bx * 64 + tx];
  }
  __syncthreads();
  #pragma unroll 4
  for (int i = 0; i < 16; ++i) {
    int r = ty4 * 16 + i;
    float v = tile[tx][r];
    size_t o = (size_t)(bx * 64 + r) * D_DIM + by * 64 + tx;
    WT[o] = v;
    WhT[o] = (_Float16)v;
  }
}

__global__ __launch_bounds__(256) void conv_wd(
    const float* __restrict__ W, unsigned short* __restrict__ o) {
  size_t g = ((size_t)blockIdx.x * 256 + threadIdx.x) * 8;
  float4 a = *(const float4*)(W + g);
  float4 b = *(const float4*)(W + g + 4);
  ushort8 v;
  v[0] = f2bf(a.x); v[1] = f2bf(a.y); v[2] = f2bf(a.z); v[3] = f2bf(a.w);
  v[4] = f2bf(b.x); v[5] = f2bf(b.y); v[6] = f2bf(b.z); v[7] = f2bf(b.w);
  *(ushort8*)(o + g) = v;
}

// ------------------------------- fp16 GEMM ---------------------------------
// Hazards (4-buf cycle, stage(t+3) in body t -> writes buf (t-1)&3):
//  - top-of-t vmcnt(4)+barrier: every wave's loads for tiles t,t+1 complete
//    and globally visible -> in-body reads of buf t AND the t+1 register
//    prefetch are safe (reads span other waves' staged data -> barrier is
//    REQUIRED, vmcnt alone is per-wave; this was the R4 NaN bug in the
//    prologue).
//  - Prefetch ds_reads of buf (t+1)&3 (issued body t) are lgkm-consumed by
//    body t+1's MFMAs, which precede the top-of-t+2 barrier, which precedes
//    body t+2's staging of that buffer.

#define STAGE(T)                                                               \
  do {                                                                         \
    const int bo_ = ((T) & 3) * 8192;                                          \
    const int kk_ = (T) * 32;                                                  \
    gload_lds16(aSrc0 + kk_, AsB + bo_ + dst0);                                \
    gload_lds16(aSrc1 + kk_, AsB + bo_ + dst1);                                \
    gload_lds16(bSrc0 + kk_, BsB + bo_ + dst0);                                \
    gload_lds16(bSrc1 + kk_, BsB + bo_ + dst1);                                \
  } while (0)

#define PREFETCH(T, AF, BF)                                                    \
  do {                                                                         \
    const int ab_ = ((T) & 3) * 8192;                                          \
    _Pragma("unroll") for (int nj = 0; nj < 4; ++nj)                           \
        BF[nj] = *(const half8*)(BsB + ab_ + bBase + nj * 512);                \
    _Pragma("unroll") for (int mi = 0; mi < 4; ++mi)                           \
        AF[mi] = *(const half8*)(AsB + ab_ + aBase + mi * 512);                \
  } while (0)

#define BODY(T, AFC, BFC, AFN, BFN, VMSTR)                                     \
  do {                                                                         \
    asm volatile("s_waitcnt " VMSTR ::: "memory");                             \
    __builtin_amdgcn_s_barrier();                                              \
    asm volatile("" ::: "memory");                                             \
    if ((T) + 3 < NTILES) STAGE((T) + 3);                                      \
    if ((T) + 1 < NTILES) PREFETCH((T) + 1, AFN, BFN);                         \
    __builtin_amdgcn_s_setprio(1);                                             \
    _Pragma("unroll") for (int mi = 0; mi < 4; ++mi)                           \
        _Pragma("unroll") for (int nj = 0; nj < 4; ++nj)                       \
        acc[mi][nj] = __builtin_amdgcn_mfma_f32_16x16x32_f16(                  \
            AFC[mi], BFC[nj], acc[mi][nj], 0, 0, 0);                           \
    __builtin_amdgcn_s_setprio(0);                                             \
    {                                                                          \
      const int ab_ = ((T) & 3) * 8192;                                        \
      half8 af2[4];                                                            \
      _Pragma("unroll") for (int mi = 0; mi < 4; ++mi)                         \
          af2[mi] = *(const half8*)(AsB + ab_ + aBase + (mi + 4) * 512);       \
      __builtin_amdgcn_s_setprio(1);                                           \
      _Pragma("unroll") for (int mi = 0; mi < 4; ++mi)                         \
          _Pragma("unroll") for (int nj = 0; nj < 4; ++nj)                     \
          acc[mi + 4][nj] = __builtin_amdgcn_mfma_f32_16x16x32_f16(            \
              af2[mi], BFC[nj], acc[mi + 4][nj], 0, 0, 0);                     \
      __builtin_amdgcn_s_setprio(0);                                           \
    }                                                                          \
  } while (0)

__global__ __launch_bounds__(512, 2) void gemm_f16(
    const _Float16* __restrict__ A, const _Float16* __restrict__ Bt,
    const float* __restrict__ latent_bias, float* __restrict__ C) {
  extern __shared__ _Float16 ldsbuf[];
  _Float16* AsB = ldsbuf;            // 4 bufs x 8192 halves (256x32)
  _Float16* BsB = ldsbuf + 4 * 8192;

  const int tid = threadIdx.x;
  const int lane = tid & 63, wave = tid >> 6;
  const int wr = wave >> 2, wc = wave & 3;

  // XCD-aware swizzle; grid = 64*16 = 1024, divisible by 8 -> bijective.
  int bid = blockIdx.x;
  int swz = (bid & 7) * (1024 >> 3) + (bid >> 3);
  const int bmBase = (swz >> 4) * 256;
  const int bnBase = (swz & 15) * 256;

  // staging: physical chunk i holds logical chunk s = i ^ ((i>>3)&3)
  const int i0 = tid, i1 = 512 + tid;
  const int s0 = i0 ^ ((i0 >> 3) & 3), s1 = i1 ^ ((i1 >> 3) & 3);
  const _Float16* aSrc0 = A + (size_t)(bmBase + (s0 >> 2)) * D_DIM + (s0 & 3) * 8;
  const _Float16* aSrc1 = A + (size_t)(bmBase + (s1 >> 2)) * D_DIM + (s1 & 3) * 8;
  const _Float16* bSrc0 = Bt + (size_t)(bnBase + (s0 >> 2)) * D_DIM + (s0 & 3) * 8;
  const _Float16* bSrc1 = Bt + (size_t)(bnBase + (s1 >> 2)) * D_DIM + (s1 & 3) * 8;
  const int dst0 = i0 * 8, dst1 = i1 * 8;  // halves within buffer (linear)

  // fragment reads: logical chunk c4 of row fr sits at physical chunk
  // c4 ^ ((fr>>1)&3)  -> bank group (row&1)*4 + (c4^f) covers all 8 groups
  // exactly 2x per quarter-wave (2-way = free).
  const int fr = lane & 15, c4 = lane >> 4;
  const int swzc = (c4 ^ ((fr >> 1) & 3)) * 8;
  const int aBase = (wr * 128 + fr) * 32 + swzc;
  const int bBase = (wc * 64 + fr) * 32 + swzc;

  f32x4 acc[8][4];
  #pragma unroll
  for (int i = 0; i < 8; ++i)
    #pragma unroll
    for (int j = 0; j < 4; ++j) acc[i][j] = f32x4{0.f, 0.f, 0.f, 0.f};

  // prologue: stage tiles 0,1,2; wait own tile-0 loads; BARRIER (other
  // waves' tile-0 slices!); then read tile-0 fragments.
  STAGE(0); STAGE(1); STAGE(2);
  asm volatile("s_waitcnt vmcnt(8)" ::: "memory");
  __builtin_amdgcn_s_barrier();
  asm volatile("" ::: "memory");
  half8 afA[4], bfA[4], afB[4], bfB[4];
  PREFETCH(0, afA, bfA);

  for (int t = 0; t < NTILES - 2; t += 2) {
    BODY(t, afA, bfA, afB, bfB, "vmcnt(4)");
    BODY(t + 1, afB, bfB, afA, bfA, "vmcnt(4)");
  }
  BODY(NTILES - 2, afA, bfA, afB, bfB, "vmcnt(0)");
  BODY(NTILES - 1, afB, bfB, afA, bfA, "vmcnt(0)");

  // epilogue
  const int crow0 = bmBase + wr * 128 + c4 * 4;
  const int ccol0 = bnBase + wc * 64 + fr;
  #pragma unroll
  for (int mi = 0; mi < 8; ++mi)
    #pragma unroll
    for (int nj = 0; nj < 4; ++nj) {
      int col = ccol0 + nj * 16;
      float lb = latent_bias[col];
      #pragma unroll
      for (int r = 0; r < 4; ++r)
        C[(size_t)(crow0 + mi * 16 + r) * D_DIM + col] = acc[mi][nj][r] + lb;
    }
}

// --------------------------- top-k classify --------------------------------
// Register-resident: each thread holds 16 values. 20-step bitwise binary
// search (bits 31..12): thr <= T64_approx < thr+2^12. Members: approx >
// Thi+MARGIN (provably in exact top-64; strictly <64 of them since
// count(>= thr+4096) < 64). Zone: [Tlo-MARGIN, Thi+MARGIN]. m+zone >= 64.
// If zone == need, zone entries are emitted directly (no rescue).

__global__ __launch_bounds__(256) void topk_classify(
    const float* __restrict__ acts, float* __restrict__ vals,
    int* __restrict__ idxs, int* __restrict__ ambIdx,
    int* __restrict__ rowMeta) {
  const int row = blockIdx.x;
  const int tid = threadIdx.x;
  const int lane = tid & 63, wave = tid >> 6;
  __shared__ int sred[4];
  const float* arow = acts + (size_t)row * D_DIM;
  unsigned su[16];
  #pragma unroll
  for (int i = 0; i < 4; ++i) {
    float4 a = *(const float4*)(arow + i * 1024 + tid * 4);
    su[4 * i + 0] = f32_sortable(a.x);
    su[4 * i + 1] = f32_sortable(a.y);
    su[4 * i + 2] = f32_sortable(a.z);
    su[4 * i + 3] = f32_sortable(a.w);
  }
  unsigned thr = 0u;
  for (int b = 31; b >= 12; --b) {
    unsigned cand = thr | (1u << b);
    int c = 0;
    #pragma unroll
    for (int i = 0; i < 16; ++i) c += (su[i] >= cand) ? 1 : 0;
    #pragma unroll
    for (int off = 32; off; off >>= 1) c += __shfl_down(c, off);
    if (lane == 0) sred[wave] = c;
    __syncthreads();
    int tot = sred[0] + sred[1] + sred[2] + sred[3];
    if (tot >= TOPK) thr = cand;
    __syncthreads();
  }
  float Tlo = sortable_f32(thr);
  float Thi = sortable_f32(thr + 4096u);
  unsigned uhi = f32_sortable(Thi + MARGIN);
  unsigned ulo = f32_sortable(Tlo - MARGIN);
  int mC = 0, aC = 0;
  #pragma unroll
  for (int i = 0; i < 16; ++i) {
    unsigned u = su[i];
    if (u > uhi) ++mC;
    else if (u >= ulo) ++aC;
  }
  int xs = mC | (aC << 16);
  #pragma unroll
  for (int off = 1; off < 64; off <<= 1) {
    int y = __shfl_up(xs, off);
    if (lane >= off) xs += y;
  }
  if (lane == 63) sred[wave] = xs;
  __syncthreads();
  int base = 0;
  for (int w = 0; w < 4; ++w)
    if (w < wave) base += sred[w];
  int tot = sred[0] + sred[1] + sred[2] + sred[3];
  int incl = base + xs;
  int mp = (incl & 0xffff) - mC;
  int ap = (incl >> 16) - aC;
  int mTot = tot & 0xffff, aTot = tot >> 16;
  const int need = TOPK - mTot;
  const bool fast = (aTot == need);  // zone exactly fills the remainder
  #pragma unroll
  for (int e = 0; e < 16; ++e) {
    unsigned u = su[e];
    int d = (e >> 2) * 1024 + tid * 4 + (e & 3);
    if (u > uhi) {
      vals[(size_t)row * TOPK + mp] = fmaxf(sortable_f32(u), 0.0f);
      idxs[(size_t)row * TOPK + mp] = d;
      ++mp;
    } else if (u >= ulo) {
      if (fast) {
        vals[(size_t)row * TOPK + mTot + ap] = fmaxf(sortable_f32(u), 0.0f);
        idxs[(size_t)row * TOPK + mTot + ap] = d;
      } else if (ap < 128) {
        ambIdx[(size_t)row * 128 + ap] = d;
      }
      ++ap;
    }
  }
  if (tid == 0) {
    rowMeta[row * 2 + 0] = mTot;
    rowMeta[row * 2 + 1] = (fast || need <= 0) ? 0 : ((aTot > 128) ? 128 : aTot);
  }
}

// ------------------------------ fp64 rescue --------------------------------

__global__ __launch_bounds__(256) void rescue(
    const float* __restrict__ x, const float* __restrict__ WT,
    const float* __restrict__ pre_bias, const float* __restrict__ latent_bias,
    const float* __restrict__ acts, const int* __restrict__ ambIdx,
    const int* __restrict__ rowMeta, float* __restrict__ vals,
    int* __restrict__ idxs) {
  const int row = blockIdx.x;
  const int m = rowMeta[row * 2 + 0];
  const int s = rowMeta[row * 2 + 1];
  const int need = TOPK - m;
  const int tid = threadIdx.x;
  if (need <= 0 || s <= 0) return;
  if (s == need) {  // residual fast path (normally resolved in classify)
    if (tid < s) {
      int d = ambIdx[(size_t)row * 128 + tid];
      float v = acts[(size_t)row * D_DIM + d];
      vals[(size_t)row * TOPK + m + tid] = fmaxf(v, 0.0f);
      idxs[(size_t)row * TOPK + m + tid] = d;
    }
    return;
  }
  __shared__ double exv[128];
  const int lane = tid & 63, wave = tid >> 6;
  const float* xr = x + (size_t)row * D_DIM;
  for (int c = wave; c < s; c += 4) {
    int d = ambIdx[(size_t)row * 128 + c];
    const float* wrow = WT + (size_t)d * D_DIM;
    double acc = 0.0;
    #pragma unroll 4
    for (int t = 0; t < 16; ++t) {
      int k0 = t * 256 + lane * 4;
      float4 xv = *(const float4*)(xr + k0);
      float4 pv = *(const float4*)(pre_bias + k0);
      float4 wv = *(const float4*)(wrow + k0);
      acc = fma((double)xv.x - (double)pv.x, (double)wv.x, acc);
      acc = fma((double)xv.y - (double)pv.y, (double)wv.y, acc);
      acc = fma((double)xv.z - (double)pv.z, (double)wv.z, acc);
      acc = fma((double)xv.w - (double)pv.w, (double)wv.w, acc);
    }
    #pragma unroll
    for (int off = 32; off; off >>= 1) acc += __shfl_down(acc, off);
    if (lane == 0) exv[c] = acc + (double)latent_bias[d];
  }
  __syncthreads();
  if (tid == 0) {
    for (int t = 0; t < need; ++t) {
      double best = -1.0e300; int besti = 1 << 30; int bestc = -1;
      for (int c = 0; c < s; ++c) {
        double v = exv[c];
        int d = ambIdx[(size_t)row * 128 + c];
        if (v > best || (v == best && d < besti)) {
          best = v; besti = d; bestc = c;
        }
      }
      vals[(size_t)row * TOPK + m + t] = fmaxf((float)best, 0.0f);
      idxs[(size_t)row * TOPK + m + t] = besti;
      exv[bestc] = -1.0e300;
    }
  }
}

// ----------------------------- reconstruct ---------------------------------

__global__ __launch_bounds__(256) void reconstruct(
    const unsigned short* __restrict__ Wd, const float* __restrict__ vals,
    const int* __restrict__ idxs, const float* __restrict__ pre_bias,
    float* __restrict__ out) {
  const int bid = blockIdx.x;
  const int cb = bid & 7, rowblk = bid >> 3;
  const int tid = threadIdx.x, lane = tid & 63, wave = tid >> 6;
  const int row = rowblk * 4 + wave;
  const int col0 = cb * 512 + lane * 8;
  __shared__ float sval[256];
  __shared__ int sidx[256];
  sval[tid] = vals[(size_t)(rowblk * 4 + (tid >> 6)) * TOPK + (tid & 63)];
  sidx[tid] = idxs[(size_t)(rowblk * 4 + (tid >> 6)) * TOPK + (tid & 63)];
  __syncthreads();
  float acc[8];
  float4 p0 = *(const float4*)(pre_bias + col0);
  float4 p1 = *(const float4*)(pre_bias + col0 + 4);
  acc[0] = p0.x; acc[1] = p0.y; acc[2] = p0.z; acc[3] = p0.w;
  acc[4] = p1.x; acc[5] = p1.y; acc[6] = p1.z; acc[7] = p1.w;
  #pragma unroll 4
  for (int k = 0; k < TOPK; ++k) {
    float v = sval[wave * 64 + k];
    int d = sidx[wave * 64 + k];
    ushort8 w = *(const ushort8*)(Wd + (size_t)d * D_DIM + col0);
    #pragma unroll
    for (int j = 0; j < 8; ++j)
      acc[j] = fmaf(v, __uint_as_float(((unsigned)w[j]) << 16), acc[j]);
  }
  float4 o0 = {acc[0], acc[1], acc[2], acc[3]};
  float4 o1 = {acc[4], acc[5], acc[6], acc[7]};
  *(float4*)(out + (size_t)row * D_DIM + col0) = o0;
  *(float4*)(out + (size_t)row * D_DIM + col0 + 4) = o1;
}

// ------------------------------- launcher ----------------------------------

extern "C" void kernel_launch(void* const* d_in, const int* in_sizes, int n_in,
                              void* d_out, int out_size, void* d_ws,
                              size_t ws_size, hipStream_t stream) {
  const float* x           = (const float*)d_in[0];
  // d_in[1] = ema_frequency_counter (unused by reference)
  const float* W_enc       = (const float*)d_in[2];
  const float* W_dec       = (const float*)d_in[3];
  const float* pre_bias    = (const float*)d_in[4];
  const float* latent_bias = (const float*)d_in[5];
  float* out = (float*)d_out;  // doubles as acts buffer, overwritten last
  char* ws = (char*)d_ws;
  size_t off = 0;
  auto alloc = [&](size_t bytes) {
    size_t o = off;
    off = (off + bytes + 255) & ~(size_t)255;
    return o;
  };
  _Float16* Xh        = (_Float16*)(ws + alloc((size_t)B_ROWS * D_DIM * 2));
  _Float16* WhT       = (_Float16*)(ws + alloc((size_t)D_DIM * D_DIM * 2));
  float* WT           = (float*)(ws + alloc((size_t)D_DIM * D_DIM * 4));
  unsigned short* Wd  = (unsigned short*)(ws + alloc((size_t)D_DIM * D_DIM * 2));
  float* vals         = (float*)(ws + alloc((size_t)B_ROWS * TOPK * 4));
  int* idxs           = (int*)(ws + alloc((size_t)B_ROWS * TOPK * 4));
  int* ambIdx         = (int*)(ws + alloc((size_t)B_ROWS * 128 * 4));
  int* rowMeta        = (int*)(ws + alloc((size_t)B_ROWS * 2 * 4));
  (void)ws_size; (void)in_sizes; (void)n_in; (void)out_size;

  // allow 128KB dynamic LDS for the GEMM (cheap, deterministic, idempotent)
  (void)hipFuncSetAttribute((const void*)gemm_f16,
                            hipFuncAttributeMaxDynamicSharedMemorySize,
                            131072);

  conv_x<<<(B_ROWS * D_DIM / 8) / 256, 256, 0, stream>>>(x, pre_bias, Xh);
  transp_w<<<dim3(D_DIM / 64, D_DIM / 64), 256, 0, stream>>>(W_enc, WhT, WT);
  conv_wd<<<((size_t)D_DIM * D_DIM / 8) / 256, 256, 0, stream>>>(W_dec, Wd);
  gemm_f16<<<(B_ROWS / 256) * (D_DIM / 256), 512, 131072, stream>>>(
      Xh, WhT, latent_bias, out);
  topk_classify<<<B_ROWS, 256, 0, stream>>>(out, vals, idxs, ambIdx, rowMeta);
  rescue<<<B_ROWS, 256, 0, stream>>>(x, WT, pre_bias, latent_bias, out,
                                     ambIdx, rowMeta, vals, idxs);
  reconstruct<<<(B_ROWS / 4) * 8, 256, 0, stream>>>(Wd, vals, idxs, pre_bias,
                                                    out);
}